// Round 16
// baseline (385.137 us; speedup 1.0000x reference)
//
#include <hip/hip_runtime.h>

#define L_SEQ 4680
#define DIMSZ 1536
#define NHEAD 12
#define HDIM 128
#define FRAME 1560
#define NKT_ALL 74            // ceil(4680/64)
#define SCALE_L2E 0.12751743f // (1/sqrt(128)) * log2(e)
#define WSZ 2359296           // 12*48*4096 halves per weight matrix
#define XSZ 7274496           // 37*48*4096 halves (also 12*74*8192)
#define PMPITCH 4736          // 37*128

typedef float f32x4 __attribute__((ext_vector_type(4)));
typedef _Float16 f16;
typedef _Float16 f16x2 __attribute__((ext_vector_type(2)));
typedef _Float16 f16x4 __attribute__((ext_vector_type(4)));
typedef _Float16 f16x8 __attribute__((ext_vector_type(8)));
typedef unsigned short u16;

__device__ __forceinline__ void gll16(const void* g, void* l) {
  __builtin_amdgcn_global_load_lds(
      (const __attribute__((address_space(1))) unsigned int*)g,
      (__attribute__((address_space(3))) unsigned int*)l, 16, 0, 0);
}

// ---- ALL fp32->fp16 splits in one dispatch: grid (48 kt, 85 rows) ----
// y<37: x rows -> xs; y>=37: weight z=(y-37)/12 rt=(y-37)%12 -> whi[z] (z=3 -> wo_hi, own slot)
__global__ __launch_bounds__(256) void split_all(
    const float* __restrict__ x,  const float* __restrict__ wq,
    const float* __restrict__ wk, const float* __restrict__ wv,
    const float* __restrict__ wo, f16* __restrict__ xs,
    f16* __restrict__ whi) {
  const int kt = blockIdx.x;
  const int y = blockIdx.y;
  const float* src; f16* dst; int R, rt;
  if (y < 37) { src = x; dst = xs; R = L_SEQ; rt = y; }
  else {
    int i = y - 37;
    int z = i / 12; rt = i - z * 12; R = DIMSZ;
    src = z == 0 ? wq : (z == 1 ? wk : (z == 2 ? wv : wo));
    dst = whi + (size_t)z * WSZ;   // z==3 (wo) gets its own 4th slot — NO vf overlay
  }
  const int t = threadIdx.x;
  const int row = t >> 1, c0 = (t & 1) * 16;
  const int gr = min(rt * 128 + row, R - 1);
  const float* s = &src[(size_t)gr * DIMSZ + kt * 32 + c0];
  float f[16];
#pragma unroll
  for (int i = 0; i < 4; ++i) *(float4*)&f[i * 4] = *(const float4*)&s[i * 4];
  size_t obase = ((size_t)(rt * 48 + kt)) * 4096 + row * 32;
#pragma unroll
  for (int cc = 0; cc < 2; ++cc) {
    f16x8 o;
#pragma unroll
    for (int i = 0; i < 8; ++i) o[i] = (f16)f[cc * 8 + i];
    int sl = (c0 >> 3) + cc;
    *(f16x8*)&dst[obase + ((sl * 8) ^ ((row & 3) * 8))] = o;
  }
}

// ---- m97-structure fp16 GEMM: 128x128 tile, BK=64, single-buffer, 3 blocks/CU ----
__global__ __launch_bounds__(256, 3) void gemm_f16_1p(
    const f16* __restrict__ A, const f16* __restrict__ Wh,
    const float* __restrict__ b0, const float* __restrict__ b1, const float* __restrict__ b2,
    float* __restrict__ C, int M) {
  __shared__ f16 SA[8192];  // [2 kc][128][32] swizzled, 16KB
  __shared__ f16 SW[8192];  // 16KB
  const int t = threadIdx.x;
  const int lane = t & 63, w = t >> 6;
  const int g = lane >> 4, ln = lane & 15;
  const int wm = w >> 1, wn = w & 1;
  const int mt = blockIdx.x, nt = blockIdx.y;
  const int which = nt / 12, ntw = nt - which * 12;
  const float* bias = which == 0 ? b0 : (which == 1 ? b1 : b2);
  const f16* srcA = A + (size_t)mt * 48 * 4096;
  const f16* srcW = Wh + ((size_t)which * 12 + ntw) * 48 * 4096;
  float* Cw = C + (size_t)which * ((size_t)L_SEQ * DIMSZ);
  f32x4 acc[4][4] = {};
  for (int kt2 = 0; kt2 < 24; ++kt2) {
    __syncthreads();                       // all waves done reading previous tile
    size_t ko = (size_t)kt2 * 8192;
#pragma unroll
    for (int i = 0; i < 4; ++i) {
      gll16(srcA + ko + (i * 256 + t) * 8, &SA[(i * 256 + t) * 8]);
      gll16(srcW + ko + (i * 256 + t) * 8, &SW[(i * 256 + t) * 8]);
    }
    __syncthreads();                       // drains vmcnt -> tile ready
#pragma unroll
    for (int kc = 0; kc < 2; ++kc) {
      f16x8 af[4], wh4[4];
#pragma unroll
      for (int mi = 0; mi < 4; ++mi) {
        int row = wm * 64 + mi * 16 + ln;
        af[mi] = *(const f16x8*)&SA[kc * 4096 + row * 32 + ((g * 8) ^ ((row & 3) * 8))];
      }
#pragma unroll
      for (int ni = 0; ni < 4; ++ni) {
        int row = wn * 64 + ni * 16 + ln;
        wh4[ni] = *(const f16x8*)&SW[kc * 4096 + row * 32 + ((g * 8) ^ ((row & 3) * 8))];
      }
      __builtin_amdgcn_s_setprio(1);
#pragma unroll
      for (int mi = 0; mi < 4; ++mi)
#pragma unroll
        for (int ni = 0; ni < 4; ++ni)
          acc[mi][ni] = __builtin_amdgcn_mfma_f32_16x16x32_f16(af[mi], wh4[ni], acc[mi][ni], 0, 0, 0);
      __builtin_amdgcn_s_setprio(0);
    }
  }
#pragma unroll
  for (int mi = 0; mi < 4; ++mi)
#pragma unroll
    for (int ni = 0; ni < 4; ++ni) {
      int col = ntw * 128 + wn * 64 + ni * 16 + ln;
      float bv = bias[col];
#pragma unroll
      for (int r = 0; r < 4; ++r) {
        int row = mt * 128 + wm * 64 + mi * 16 + 4 * g + r;
        if (row < M) Cw[(size_t)row * DIMSZ + col] = acc[mi][ni][r] + bv;
      }
    }
}

// ------------- RMSNorm + RoPE -> fp16. y=0: q16 [L][1536] pre-scaled; y=1: k16 blocked -------------
__global__ __launch_bounds__(256) void norm_rope(
    const float* __restrict__ qf, const float* __restrict__ kf,
    const float* __restrict__ gq, const float* __restrict__ gk,
    const float* __restrict__ freqs, f16* __restrict__ q16, f16* __restrict__ k16) {
  const int pos = blockIdx.x;
  const bool isq = blockIdx.y == 0;
  const float* row = (isq ? qf : kf) + (size_t)pos * DIMSZ;
  const float* g = isq ? gq : gk;
  const int t = threadIdx.x;
  float2 ab[3];
  float ss = 0.f;
#pragma unroll
  for (int i = 0; i < 3; ++i) {
    ab[i] = *(const float2*)&row[2 * (t + 256 * i)];
    ss += ab[i].x * ab[i].x + ab[i].y * ab[i].y;
  }
#pragma unroll
  for (int m = 32; m; m >>= 1) ss += __shfl_xor(ss, m);
  __shared__ float part[4];
  if ((t & 63) == 0) part[t >> 6] = ss;
  __syncthreads();
  const float tot = part[0] + part[1] + part[2] + part[3];
  float scale = rsqrtf(tot * (1.f / DIMSZ) + 1e-6f);
  if (isq) scale *= SCALE_L2E;
  const int f = pos / FRAME;
  const int rem = pos - f * FRAME;
  const int hh = rem / 52;
  const int ww = rem - hh * 52;
  const int kt = pos >> 6, kk = pos & 63;
#pragma unroll
  for (int i = 0; i < 3; ++i) {
    const int p = t + 256 * i;
    const int c = p & 63;
    const int h = p >> 6;
    const int pr = c < 22 ? f : (c < 43 ? hh : ww);
    const float cs = freqs[(pr * 64 + c) * 2 + 0];
    const float sn = freqs[(pr * 64 + c) * 2 + 1];
    const float a = ab[i].x * scale * g[2 * p];
    const float b = ab[i].y * scale * g[2 * p + 1];
    f16x2 o;
    o[0] = (f16)(a * cs - b * sn);
    o[1] = (f16)(a * sn + b * cs);
    if (isq) {
      *(f16x2*)&q16[(size_t)pos * DIMSZ + 2 * p] = o;
    } else {
      const int s = c >> 2;
      size_t base = ((size_t)(h * NKT_ALL + kt)) << 13;
      *(f16x2*)&k16[base + kk * 128 + ((s * 8) ^ ((kk & 7) * 8)) + (c & 3) * 2] = o;
    }
  }
}

// ---- V -> fp16, transposed + PV-packed key order, blocked [head][tile][d=128][chunk perm] ----
__global__ __launch_bounds__(256) void vconvert(const float* __restrict__ v, f16* __restrict__ v16) {
  __shared__ f16 Ls[64][136];
  const int kt = blockIdx.x, h = blockIdx.y, t = threadIdx.x;
#pragma unroll
  for (int p = 0; p < 8; ++p) {
    int e = p * 1024 + t * 4;
    int kk = e >> 7, d = e & 127;
    int gr = kt * 64 + kk;
    float4 val = make_float4(0.f, 0.f, 0.f, 0.f);
    if (gr < L_SEQ) val = *(const float4*)&v[(size_t)gr * DIMSZ + h * HDIM + d];
    f16x4 o;
    o[0] = (f16)val.x; o[1] = (f16)val.y; o[2] = (f16)val.z; o[3] = (f16)val.w;
    *(f16x4*)&Ls[kk][d] = o;
  }
  __syncthreads();
  f16* out = v16 + (((size_t)(h * NKT_ALL + kt)) << 13);
#pragma unroll
  for (int p = 0; p < 4; ++p) {
    int idx = p * 256 + t;         // 1024: d (7b) x chunk c (3b)
    int d = idx >> 3, c = idx & 7;
    const int nbb = (c & 1) * 2;   // 2*nbp
    const int g4 = (c >> 1) * 4;   // 4g
    f16x8 o;
#pragma unroll
    for (int i = 0; i < 8; ++i) o[i] = Ls[(nbb + (i >> 2)) * 16 + g4 + (i & 3)][d];
    *(f16x8*)&out[d * 64 + 8 * (c ^ (d & 7))] = o;
  }
}

// ===== flash attention v10: K gll16-dbuf + V single-buffer reg-prefetch, 53KB LDS =====
__global__ __launch_bounds__(256, 2) void attn_split(
    const f16* __restrict__ q16, const f16* __restrict__ k16,
    const f16* __restrict__ v16, float* __restrict__ pO,
    float* __restrict__ pm, float* __restrict__ pl) {
  __shared__ f16 Ks[2][8192];   // [key=64][d=128] swizzled, 32KB (dbuf)
  __shared__ f16 Vt[8192];      // [d=128][key packed] swizzled, 16KB (single)
  __shared__ float Os[4][16][20];
  const int b = blockIdx.x;           // 888 blocks, heavy-first
  const int qt = 36 - b / 24;
  const int rem = b % 24;
  const int s = rem / 12;
  const int h = rem % 12;
  const int q0 = qt * 128;
  const int t = threadIdx.x;
  const int lane = t & 63, w = t >> 6;
  const int g = lane >> 4, ln = lane & 15;

  f16x8 qa[2][4];
  int klim[2];
  float m_run[2], l_run[2];
#pragma unroll
  for (int mi = 0; mi < 2; ++mi) {
    int qrow = min(q0 + w * 32 + mi * 16 + ln, L_SEQ - 1);
    klim[mi] = (qrow / FRAME + 1) * FRAME;
    m_run[mi] = -1e30f;
    l_run[mi] = 0.f;
    const f16* qb = &q16[(size_t)qrow * DIMSZ + h * HDIM + g * 8];
#pragma unroll
    for (int kc = 0; kc < 4; ++kc) qa[mi][kc] = *(const f16x8*)&qb[kc * 32];
  }
  const int klim0 = __shfl(klim[0], 0);  // wave-min (rows ascend)
  f32x4 acc[2][8] = {};  // O^T raw partial

  const int rmax = min(q0 + 127, L_SEQ - 1);
  const int nkt = ((rmax / FRAME + 1) * FRAME + 63) >> 6;
  const size_t hbase = ((size_t)h * NKT_ALL) << 13;

  f16x8 vv0, vv1, vv2, vv3;  // named V staging regs (rule #20: no arrays)
  // prologue: V[s] -> regs -> Vt; K[s] -> gll -> Ks[0]
  {
    const f16* tv = v16 + hbase + ((size_t)s << 13) + t * 8;
    vv0 = *(const f16x8*)(tv);
    vv1 = *(const f16x8*)(tv + 2048);
    vv2 = *(const f16x8*)(tv + 4096);
    vv3 = *(const f16x8*)(tv + 6144);
    f16* lv = Vt + t * 8;
    *(f16x8*)(lv) = vv0;
    *(f16x8*)(lv + 2048) = vv1;
    *(f16x8*)(lv + 4096) = vv2;
    *(f16x8*)(lv + 6144) = vv3;
    const f16* tk = k16 + hbase + ((size_t)s << 13);
#pragma unroll
    for (int i = 0; i < 4; ++i) gll16(tk + (i * 256 + t) * 8, &Ks[0][(i * 256 + t) * 8]);
  }
  int cur = 0;
  for (int kt = s; kt < nkt; kt += 2) {
    __syncthreads();   // A: drains K gll + V reg-loads; Vt writes visible; all past prev PV
    const bool more = (kt + 2 < nkt);
    if (more) {
      size_t tb = hbase + ((size_t)(kt + 2) << 13);
      const f16* tk = k16 + tb;
#pragma unroll
      for (int i = 0; i < 4; ++i) gll16(tk + (i * 256 + t) * 8, &Ks[cur ^ 1][(i * 256 + t) * 8]);
      const f16* tv = v16 + tb + t * 8;
      vv0 = *(const f16x8*)(tv);
      vv1 = *(const f16x8*)(tv + 2048);
      vv2 = *(const f16x8*)(tv + 4096);
      vv3 = *(const f16x8*)(tv + 6144);
    }
    const f16* Kb = Ks[cur];

    // ---- S^T = K Q^T, K frags shared across both mi strips ----
    f32x4 st[2][4] = {};
    __builtin_amdgcn_s_setprio(1);
#pragma unroll
    for (int nb = 0; nb < 4; ++nb) {
      int row = nb * 16 + ln;
#pragma unroll
      for (int kc = 0; kc < 4; ++kc) {
        f16x8 kb = *(const f16x8*)&Kb[row * 128 + ((g * 8 + kc * 32) ^ ((row & 7) * 8))];
        st[0][nb] = __builtin_amdgcn_mfma_f32_16x16x32_f16(kb, qa[0][kc], st[0][nb], 0, 0, 0);
        st[1][nb] = __builtin_amdgcn_mfma_f32_16x16x32_f16(kb, qa[1][kc], st[1][nb], 0, 0, 0);
      }
    }
    __builtin_amdgcn_s_setprio(0);

    // ---- per-lane online softmax per mi; in-place masking; defer-max ----
    f16x4 pb[2][4];
    const bool boundary = (kt * 64 + 64 > klim0);
#pragma unroll
    for (int mi = 0; mi < 2; ++mi) {
      float rm = -1e30f;
      if (boundary) {
#pragma unroll
        for (int nb = 0; nb < 4; ++nb)
#pragma unroll
          for (int r = 0; r < 4; ++r) {
            int key = kt * 64 + nb * 16 + 4 * g + r;
            float val = st[mi][nb][r];
            if (key >= klim[mi]) val = -1e30f;
            st[mi][nb][r] = val;
            rm = fmaxf(rm, val);
          }
      } else {
#pragma unroll
        for (int nb = 0; nb < 4; ++nb)
#pragma unroll
          for (int r = 0; r < 4; ++r) rm = fmaxf(rm, st[mi][nb][r]);
      }
      rm = fmaxf(rm, __shfl_xor(rm, 16));
      rm = fmaxf(rm, __shfl_xor(rm, 32));
      if (!__all(rm - m_run[mi] <= 8.0f)) {   // defer-max (T13)
        float mn = fmaxf(m_run[mi], rm);
        float fs = exp2f(m_run[mi] - mn);
        m_run[mi] = mn;
        l_run[mi] *= fs;
#pragma unroll
        for (int db = 0; db < 8; ++db)
#pragma unroll
          for (int r = 0; r < 4; ++r) acc[mi][db][r] *= fs;
      }
      float sm = 0.f;
#pragma unroll
      for (int nb = 0; nb < 4; ++nb)
#pragma unroll
        for (int r = 0; r < 4; ++r) {
          float e = exp2f(st[mi][nb][r] - m_run[mi]);
          sm += e;
          pb[mi][nb][r] = (f16)e;
        }
      sm += __shfl_xor(sm, 16);
      sm += __shfl_xor(sm, 32);
      l_run[mi] += sm;
    }

    // ---- O^T += V^T P^T, packed-V: one b128 covers two nb fragments ----
    __builtin_amdgcn_s_setprio(1);
#pragma unroll
    for (int db = 0; db < 8; ++db) {
      int d = db * 16 + ln;
#pragma unroll
      for (int nbp = 0; nbp < 2; ++nbp) {
        f16x8 vvv = *(const f16x8*)&Vt[d * 64 + 8 * ((g * 2 + nbp) ^ (d & 7))];
        f16x4 vlo = {vvv[0], vvv[1], vvv[2], vvv[3]};
        f16x4 vhi = {vvv[4], vvv[5], vvv[6], vvv[7]};
        acc[0][db] = __builtin_amdgcn_mfma_f32_16x16x16f16(vlo, pb[0][2 * nbp], acc[0][db], 0, 0, 0);
        acc[1][db] = __builtin_amdgcn_mfma_f32_16x16x16f16(vlo, pb[1][2 * nbp], acc[1][db], 0, 0, 0);
        acc[0][db] = __builtin_amdgcn_mfma_f32_16x16x16f16(vhi, pb[0][2 * nbp + 1], acc[0][db], 0, 0, 0);
        acc[1][db] = __builtin_amdgcn_mfma_f32_16x16x16f16(vhi, pb[1][2 * nbp + 1], acc[1][db], 0, 0, 0);
      }
    }
    __builtin_amdgcn_s_setprio(0);

    __syncthreads();   // B: all waves done reading Vt (and Ks[cur])
    if (more) {        // write-late: V[kt+2] regs -> Vt (drained data, private->shared)
      f16* lv = Vt + t * 8;
      *(f16x8*)(lv) = vv0;
      *(f16x8*)(lv + 2048) = vv1;
      *(f16x8*)(lv + 4096) = vv2;
      *(f16x8*)(lv + 6144) = vv3;
    }
    cur ^= 1;
  }

  // ---- epilogue: raw partials. pm/pl per row (g==0 lanes); pO via transpose ----
#pragma unroll
  for (int mi = 0; mi < 2; ++mi) {
    int qrow = q0 + w * 32 + mi * 16 + ln;   // < 4736 always
    if (g == 0) {
      pm[((size_t)s * 12 + h) * PMPITCH + qrow] = m_run[mi];
      pl[((size_t)s * 12 + h) * PMPITCH + qrow] = l_run[mi];
    }
#pragma unroll
    for (int db = 0; db < 8; ++db) {
      *(f32x4*)&Os[w][ln][4 * g] = acc[mi][db];
      asm volatile("s_waitcnt lgkmcnt(0)" ::: "memory");
#pragma unroll
      for (int r = 0; r < 4; ++r) {
        int q = q0 + w * 32 + mi * 16 + 4 * g + r;
        float val = Os[w][4 * g + r][ln];
        if (q < L_SEQ)
          pO[((size_t)s * L_SEQ + q) * DIMSZ + h * HDIM + db * 16 + ln] = val;
      }
      asm volatile("s_waitcnt lgkmcnt(0)" ::: "memory");
    }
  }
}

// ---- combine split-K partials -> aos fp16 blocked-swizzled (A of out-GEMM) ----
__global__ __launch_bounds__(256) void combine_k(
    const float* __restrict__ pO, const float* __restrict__ pm,
    const float* __restrict__ pl, f16* __restrict__ aos) {
  const int qt = blockIdx.x, h = blockIdx.y, t = threadIdx.x;
  const int row = t >> 1, d0 = (t & 1) * 64;
  const int q = min(qt * 128 + row, L_SEQ - 1);
  const float m0 = pm[(size_t)h * PMPITCH + q];
  const float m1 = pm[((size_t)12 + h) * PMPITCH + q];
  const float l0 = pl[(size_t)h * PMPITCH + q];
  const float l1 = pl[((size_t)12 + h) * PMPITCH + q];
  const float m = fmaxf(m0, m1);
  float w0 = exp2f(m0 - m), w1 = exp2f(m1 - m);
  const float rinv = 1.f / (w0 * l0 + w1 * l1);
  w0 *= rinv; w1 *= rinv;
  const float* o0 = &pO[(size_t)q * DIMSZ + h * HDIM + d0];
  const float* o1 = &pO[((size_t)L_SEQ + q) * DIMSZ + h * HDIM + d0];
  f16* outbase = aos + ((size_t)qt * 48 + h * 4) * 4096 + row * 32;
#pragma unroll
  for (int c8 = 0; c8 < 8; ++c8) {
    float a[8], bvals[8];
    *(float4*)&a[0] = *(const float4*)&o0[c8 * 8];
    *(float4*)&a[4] = *(const float4*)&o0[c8 * 8 + 4];
    *(float4*)&bvals[0] = *(const float4*)&o1[c8 * 8];
    *(float4*)&bvals[4] = *(const float4*)&o1[c8 * 8 + 4];
    f16x8 ov;
#pragma unroll
    for (int i = 0; i < 8; ++i) ov[i] = (f16)(w0 * a[i] + w1 * bvals[i]);
    int d = d0 + c8 * 8;
    int ktb = d >> 5;
    int s8 = (d & 31) >> 3;
    *(f16x8*)&outbase[(size_t)ktb * 4096 + ((s8 * 8) ^ ((row & 3) * 8))] = ov;
  }
}

extern "C" void kernel_launch(void* const* d_in, const int* in_sizes, int n_in,
                              void* d_out, int out_size, void* d_ws, size_t ws_size,
                              hipStream_t stream) {
  const float* x  = (const float*)d_in[0];
  const float* wq = (const float*)d_in[1];
  const float* bq = (const float*)d_in[2];
  const float* wk = (const float*)d_in[3];
  const float* bk = (const float*)d_in[4];
  const float* wv = (const float*)d_in[5];
  const float* bv = (const float*)d_in[6];
  const float* wo = (const float*)d_in[7];
  const float* bo = (const float*)d_in[8];
  const float* gq = (const float*)d_in[9];
  const float* gk = (const float*)d_in[10];
  const float* freqs = (const float*)d_in[11];
  float* out = (float*)d_out;
  float* ws = (float*)d_ws;

  const size_t LD = (size_t)L_SEQ * DIMSZ;   // 7,188,480

  float* qf = ws;                  // LD f32  -> later pO split 0
  float* kf = ws + LD;             // LD f32  -> later pO split 1
  float* vf = ws + 2 * LD;         // LD f32  -> later aos/pm/pl
  f16* xs  = (f16*)(ws + 3 * LD);  // XSZ halves -> later q16
  f16* k16 = xs + XSZ;
  f16* v16 = k16 + XSZ;
  f16* whi = v16 + XSZ;            // 4*WSZ (wq,wk,wv,wo hi) — wo has its OWN slot now
  // overlays:
  f16* q16 = xs;                                   // after QKV GEMM
  float* pO = qf;                                  // 2*LD f32 over qf+kf
  f16* aos = (f16*)vf;                             // XSZ halves
  float* pm = vf + XSZ / 2;                        // 113,664 f32
  float* pl = pm + 2 * 12 * PMPITCH;               // 113,664 f32
  f16* wo_hi = whi + 3 * (size_t)WSZ;              // own slot (no overlay!)

  dim3 blk(256);
  split_all<<<dim3(48, 85), blk, 0, stream>>>(x, wq, wk, wv, wo, xs, whi);
  gemm_f16_1p<<<dim3(37, 36), blk, 0, stream>>>(xs, whi, bq, bk, bv, qf, L_SEQ);
  norm_rope<<<dim3(L_SEQ, 2), blk, 0, stream>>>(qf, kf, gq, gk, freqs, q16, k16);
  vconvert<<<dim3(NKT_ALL, NHEAD), blk, 0, stream>>>(vf, v16);
  attn_split<<<dim3(37 * 24), blk, 0, stream>>>(q16, k16, v16, pO, pm, pl);
  combine_k<<<dim3(37, 12), blk, 0, stream>>>(pO, pm, pl, aos);
  gemm_f16_1p<<<dim3(37, 12), blk, 0, stream>>>(aos, wo_hi, bo, bo, bo, out, L_SEQ);
}

// Round 17
// 370.509 us; speedup vs baseline: 1.0395x; 1.0395x over previous
//
#include <hip/hip_runtime.h>

#define L_SEQ 4680
#define DIMSZ 1536
#define NHEAD 12
#define HDIM 128
#define FRAME 1560
#define NKT_ALL 74            // ceil(4680/64)
#define SCALE_L2E 0.12751743f // (1/sqrt(128)) * log2(e)
#define WSZ 2359296           // 12*48*4096 halves per weight matrix
#define XSZ 7274496           // 37*48*4096 halves (also 12*74*8192)
#define PMPITCH 4736          // 37*128
#define LDSZ ((size_t)L_SEQ * DIMSZ)

typedef float f32x4 __attribute__((ext_vector_type(4)));
typedef _Float16 f16;
typedef _Float16 f16x2 __attribute__((ext_vector_type(2)));
typedef _Float16 f16x4 __attribute__((ext_vector_type(4)));
typedef _Float16 f16x8 __attribute__((ext_vector_type(8)));
typedef unsigned short u16;

__device__ __forceinline__ void gll16(const void* g, void* l) {
  __builtin_amdgcn_global_load_lds(
      (const __attribute__((address_space(1))) unsigned int*)g,
      (__attribute__((address_space(3))) unsigned int*)l, 16, 0, 0);
}

// ---- ALL fp32->fp16 splits in one dispatch: grid (48 kt, 85 rows) ----
__global__ __launch_bounds__(256) void split_all(
    const float* __restrict__ x,  const float* __restrict__ wq,
    const float* __restrict__ wk, const float* __restrict__ wv,
    const float* __restrict__ wo, f16* __restrict__ xs,
    f16* __restrict__ whi) {
  const int kt = blockIdx.x;
  const int y = blockIdx.y;
  const float* src; f16* dst; int R, rt;
  if (y < 37) { src = x; dst = xs; R = L_SEQ; rt = y; }
  else {
    int i = y - 37;
    int z = i / 12; rt = i - z * 12; R = DIMSZ;
    src = z == 0 ? wq : (z == 1 ? wk : (z == 2 ? wv : wo));
    dst = whi + (size_t)z * WSZ;
  }
  const int t = threadIdx.x;
  const int row = t >> 1, c0 = (t & 1) * 16;
  const int gr = min(rt * 128 + row, R - 1);
  const float* s = &src[(size_t)gr * DIMSZ + kt * 32 + c0];
  float f[16];
#pragma unroll
  for (int i = 0; i < 4; ++i) *(float4*)&f[i * 4] = *(const float4*)&s[i * 4];
  size_t obase = ((size_t)(rt * 48 + kt)) * 4096 + row * 32;
#pragma unroll
  for (int cc = 0; cc < 2; ++cc) {
    f16x8 o;
#pragma unroll
    for (int i = 0; i < 8; ++i) o[i] = (f16)f[cc * 8 + i];
    int sl = (c0 >> 3) + cc;
    *(f16x8*)&dst[obase + ((sl * 8) ^ ((row & 3) * 8))] = o;
  }
}

// ---- fp16 GEMM: 128x128 tile, BK=64, single-buffer. OUT16: fp16 C (QKV) else fp32 ----
template <int OUT16>
__global__ __launch_bounds__(256, 3) void gemm_f16_t(
    const f16* __restrict__ A, const f16* __restrict__ Wh,
    const float* __restrict__ b0, const float* __restrict__ b1, const float* __restrict__ b2,
    float* __restrict__ C, f16* __restrict__ C16, int M) {
  __shared__ f16 SA[8192];
  __shared__ f16 SW[8192];
  const int t = threadIdx.x;
  const int lane = t & 63, w = t >> 6;
  const int g = lane >> 4, ln = lane & 15;
  const int wm = w >> 1, wn = w & 1;
  const int mt = blockIdx.x, nt = blockIdx.y;
  const int which = nt / 12, ntw = nt - which * 12;
  const float* bias = which == 0 ? b0 : (which == 1 ? b1 : b2);
  const f16* srcA = A + (size_t)mt * 48 * 4096;
  const f16* srcW = Wh + ((size_t)which * 12 + ntw) * 48 * 4096;
  f32x4 acc[4][4] = {};
  for (int kt2 = 0; kt2 < 24; ++kt2) {
    __syncthreads();
    size_t ko = (size_t)kt2 * 8192;
#pragma unroll
    for (int i = 0; i < 4; ++i) {
      gll16(srcA + ko + (i * 256 + t) * 8, &SA[(i * 256 + t) * 8]);
      gll16(srcW + ko + (i * 256 + t) * 8, &SW[(i * 256 + t) * 8]);
    }
    __syncthreads();
#pragma unroll
    for (int kc = 0; kc < 2; ++kc) {
      f16x8 af[4], wh4[4];
#pragma unroll
      for (int mi = 0; mi < 4; ++mi) {
        int row = wm * 64 + mi * 16 + ln;
        af[mi] = *(const f16x8*)&SA[kc * 4096 + row * 32 + ((g * 8) ^ ((row & 3) * 8))];
      }
#pragma unroll
      for (int ni = 0; ni < 4; ++ni) {
        int row = wn * 64 + ni * 16 + ln;
        wh4[ni] = *(const f16x8*)&SW[kc * 4096 + row * 32 + ((g * 8) ^ ((row & 3) * 8))];
      }
      __builtin_amdgcn_s_setprio(1);
#pragma unroll
      for (int mi = 0; mi < 4; ++mi)
#pragma unroll
        for (int ni = 0; ni < 4; ++ni)
          acc[mi][ni] = __builtin_amdgcn_mfma_f32_16x16x32_f16(af[mi], wh4[ni], acc[mi][ni], 0, 0, 0);
      __builtin_amdgcn_s_setprio(0);
    }
  }
#pragma unroll
  for (int mi = 0; mi < 4; ++mi)
#pragma unroll
    for (int ni = 0; ni < 4; ++ni) {
      int col = ntw * 128 + wn * 64 + ni * 16 + ln;
      float bv = bias[col];
#pragma unroll
      for (int r = 0; r < 4; ++r) {
        int row = mt * 128 + wm * 64 + mi * 16 + 4 * g + r;
        if (row < M) {
          if (OUT16)
            C16[(size_t)which * LDSZ + (size_t)row * DIMSZ + col] = (f16)(acc[mi][ni][r] + bv);
          else
            C[(size_t)which * LDSZ + (size_t)row * DIMSZ + col] = acc[mi][ni][r] + bv;
        }
      }
    }
}

// ---- merged: RMSNorm+RoPE (bx<9360) | V transpose-pack (bx>=9360) ----
__global__ __launch_bounds__(256) void norm_v(
    const f16* __restrict__ qh, const f16* __restrict__ kh,
    const float* __restrict__ gq, const float* __restrict__ gk,
    const float* __restrict__ freqs, f16* __restrict__ q16, f16* __restrict__ k16,
    const f16* __restrict__ vh, f16* __restrict__ v16) {
  __shared__ f16 Ls[64][136];
  __shared__ float part[4];
  const int bx = blockIdx.x;
  const int t = threadIdx.x;
  if (bx < 9360) {
    // ---- norm+rope path ----
    const int pos = bx >> 1;
    const bool isq = (bx & 1) == 0;
    const f16* row = (isq ? qh : kh) + (size_t)pos * DIMSZ;
    const float* g = isq ? gq : gk;
    float2 ab[3];
    float ss = 0.f;
#pragma unroll
    for (int i = 0; i < 3; ++i) {
      f16x2 v = *(const f16x2*)&row[2 * (t + 256 * i)];
      ab[i].x = (float)v[0];
      ab[i].y = (float)v[1];
      ss += ab[i].x * ab[i].x + ab[i].y * ab[i].y;
    }
#pragma unroll
    for (int m = 32; m; m >>= 1) ss += __shfl_xor(ss, m);
    if ((t & 63) == 0) part[t >> 6] = ss;
    __syncthreads();
    const float tot = part[0] + part[1] + part[2] + part[3];
    float scale = rsqrtf(tot * (1.f / DIMSZ) + 1e-6f);
    if (isq) scale *= SCALE_L2E;
    const int f = pos / FRAME;
    const int rem = pos - f * FRAME;
    const int hh = rem / 52;
    const int ww = rem - hh * 52;
    const int kt = pos >> 6, kk = pos & 63;
#pragma unroll
    for (int i = 0; i < 3; ++i) {
      const int p = t + 256 * i;
      const int c = p & 63;
      const int h = p >> 6;
      const int pr = c < 22 ? f : (c < 43 ? hh : ww);
      const float cs = freqs[(pr * 64 + c) * 2 + 0];
      const float sn = freqs[(pr * 64 + c) * 2 + 1];
      const float a = ab[i].x * scale * g[2 * p];
      const float b = ab[i].y * scale * g[2 * p + 1];
      f16x2 o;
      o[0] = (f16)(a * cs - b * sn);
      o[1] = (f16)(a * sn + b * cs);
      if (isq) {
        *(f16x2*)&q16[(size_t)pos * DIMSZ + 2 * p] = o;
      } else {
        const int s = c >> 2;
        size_t base = ((size_t)(h * NKT_ALL + kt)) << 13;
        *(f16x2*)&k16[base + kk * 128 + ((s * 8) ^ ((kk & 7) * 8)) + (c & 3) * 2] = o;
      }
    }
  } else {
    // ---- V transpose + PV-packed layout path ----
    const int idx = bx - 9360;
    const int kt = idx % NKT_ALL, h = idx / NKT_ALL;
#pragma unroll
    for (int p = 0; p < 8; ++p) {
      int e = p * 1024 + t * 4;
      int kk = e >> 7, d = e & 127;
      int gr = min(kt * 64 + kk, L_SEQ - 1);
      f16x4 o = *(const f16x4*)&vh[(size_t)gr * DIMSZ + h * HDIM + d];
      *(f16x4*)&Ls[kk][d] = o;
    }
    __syncthreads();
    f16* out = v16 + (((size_t)(h * NKT_ALL + kt)) << 13);
#pragma unroll
    for (int p = 0; p < 4; ++p) {
      int idx2 = p * 256 + t;
      int d = idx2 >> 3, c = idx2 & 7;
      const int nbb = (c & 1) * 2;
      const int g4 = (c >> 1) * 4;
      f16x8 o;
#pragma unroll
      for (int i = 0; i < 8; ++i) o[i] = Ls[(nbb + (i >> 2)) * 16 + g4 + (i & 3)][d];
      *(f16x8*)&out[d * 64 + 8 * (c ^ (d & 7))] = o;
    }
  }
}

// ===== flash attention v10: K gll16-dbuf + V single-buffer reg-prefetch, 53KB LDS =====
__global__ __launch_bounds__(256, 2) void attn_split(
    const f16* __restrict__ q16, const f16* __restrict__ k16,
    const f16* __restrict__ v16, float* __restrict__ pO,
    float* __restrict__ pm, float* __restrict__ pl) {
  __shared__ f16 Ks[2][8192];
  __shared__ f16 Vt[8192];
  __shared__ float Os[4][16][20];
  const int b = blockIdx.x;
  const int qt = 36 - b / 24;
  const int rem = b % 24;
  const int s = rem / 12;
  const int h = rem % 12;
  const int q0 = qt * 128;
  const int t = threadIdx.x;
  const int lane = t & 63, w = t >> 6;
  const int g = lane >> 4, ln = lane & 15;

  f16x8 qa[2][4];
  int klim[2];
  float m_run[2], l_run[2];
#pragma unroll
  for (int mi = 0; mi < 2; ++mi) {
    int qrow = min(q0 + w * 32 + mi * 16 + ln, L_SEQ - 1);
    klim[mi] = (qrow / FRAME + 1) * FRAME;
    m_run[mi] = -1e30f;
    l_run[mi] = 0.f;
    const f16* qb = &q16[(size_t)qrow * DIMSZ + h * HDIM + g * 8];
#pragma unroll
    for (int kc = 0; kc < 4; ++kc) qa[mi][kc] = *(const f16x8*)&qb[kc * 32];
  }
  const int klim0 = __shfl(klim[0], 0);
  f32x4 acc[2][8] = {};

  const int rmax = min(q0 + 127, L_SEQ - 1);
  const int nkt = ((rmax / FRAME + 1) * FRAME + 63) >> 6;
  const size_t hbase = ((size_t)h * NKT_ALL) << 13;

  f16x8 vv0, vv1, vv2, vv3;
  {
    const f16* tv = v16 + hbase + ((size_t)s << 13) + t * 8;
    vv0 = *(const f16x8*)(tv);
    vv1 = *(const f16x8*)(tv + 2048);
    vv2 = *(const f16x8*)(tv + 4096);
    vv3 = *(const f16x8*)(tv + 6144);
    f16* lv = Vt + t * 8;
    *(f16x8*)(lv) = vv0;
    *(f16x8*)(lv + 2048) = vv1;
    *(f16x8*)(lv + 4096) = vv2;
    *(f16x8*)(lv + 6144) = vv3;
    const f16* tk = k16 + hbase + ((size_t)s << 13);
#pragma unroll
    for (int i = 0; i < 4; ++i) gll16(tk + (i * 256 + t) * 8, &Ks[0][(i * 256 + t) * 8]);
  }
  int cur = 0;
  for (int kt = s; kt < nkt; kt += 2) {
    __syncthreads();
    const bool more = (kt + 2 < nkt);
    if (more) {
      size_t tb = hbase + ((size_t)(kt + 2) << 13);
      const f16* tk = k16 + tb;
#pragma unroll
      for (int i = 0; i < 4; ++i) gll16(tk + (i * 256 + t) * 8, &Ks[cur ^ 1][(i * 256 + t) * 8]);
      const f16* tv = v16 + tb + t * 8;
      vv0 = *(const f16x8*)(tv);
      vv1 = *(const f16x8*)(tv + 2048);
      vv2 = *(const f16x8*)(tv + 4096);
      vv3 = *(const f16x8*)(tv + 6144);
    }
    const f16* Kb = Ks[cur];

    f32x4 st[2][4] = {};
    __builtin_amdgcn_s_setprio(1);
#pragma unroll
    for (int nb = 0; nb < 4; ++nb) {
      int row = nb * 16 + ln;
#pragma unroll
      for (int kc = 0; kc < 4; ++kc) {
        f16x8 kb = *(const f16x8*)&Kb[row * 128 + ((g * 8 + kc * 32) ^ ((row & 7) * 8))];
        st[0][nb] = __builtin_amdgcn_mfma_f32_16x16x32_f16(kb, qa[0][kc], st[0][nb], 0, 0, 0);
        st[1][nb] = __builtin_amdgcn_mfma_f32_16x16x32_f16(kb, qa[1][kc], st[1][nb], 0, 0, 0);
      }
    }
    __builtin_amdgcn_s_setprio(0);

    f16x4 pb[2][4];
    const bool boundary = (kt * 64 + 64 > klim0);
#pragma unroll
    for (int mi = 0; mi < 2; ++mi) {
      float rm = -1e30f;
      if (boundary) {
#pragma unroll
        for (int nb = 0; nb < 4; ++nb)
#pragma unroll
          for (int r = 0; r < 4; ++r) {
            int key = kt * 64 + nb * 16 + 4 * g + r;
            float val = st[mi][nb][r];
            if (key >= klim[mi]) val = -1e30f;
            st[mi][nb][r] = val;
            rm = fmaxf(rm, val);
          }
      } else {
#pragma unroll
        for (int nb = 0; nb < 4; ++nb)
#pragma unroll
          for (int r = 0; r < 4; ++r) rm = fmaxf(rm, st[mi][nb][r]);
      }
      rm = fmaxf(rm, __shfl_xor(rm, 16));
      rm = fmaxf(rm, __shfl_xor(rm, 32));
      if (!__all(rm - m_run[mi] <= 8.0f)) {
        float mn = fmaxf(m_run[mi], rm);
        float fs = exp2f(m_run[mi] - mn);
        m_run[mi] = mn;
        l_run[mi] *= fs;
#pragma unroll
        for (int db = 0; db < 8; ++db)
#pragma unroll
          for (int r = 0; r < 4; ++r) acc[mi][db][r] *= fs;
      }
      float sm = 0.f;
#pragma unroll
      for (int nb = 0; nb < 4; ++nb)
#pragma unroll
        for (int r = 0; r < 4; ++r) {
          float e = exp2f(st[mi][nb][r] - m_run[mi]);
          sm += e;
          pb[mi][nb][r] = (f16)e;
        }
      sm += __shfl_xor(sm, 16);
      sm += __shfl_xor(sm, 32);
      l_run[mi] += sm;
    }

    __builtin_amdgcn_s_setprio(1);
#pragma unroll
    for (int db = 0; db < 8; ++db) {
      int d = db * 16 + ln;
#pragma unroll
      for (int nbp = 0; nbp < 2; ++nbp) {
        f16x8 vvv = *(const f16x8*)&Vt[d * 64 + 8 * ((g * 2 + nbp) ^ (d & 7))];
        f16x4 vlo = {vvv[0], vvv[1], vvv[2], vvv[3]};
        f16x4 vhi = {vvv[4], vvv[5], vvv[6], vvv[7]};
        acc[0][db] = __builtin_amdgcn_mfma_f32_16x16x16f16(vlo, pb[0][2 * nbp], acc[0][db], 0, 0, 0);
        acc[1][db] = __builtin_amdgcn_mfma_f32_16x16x16f16(vlo, pb[1][2 * nbp], acc[1][db], 0, 0, 0);
        acc[0][db] = __builtin_amdgcn_mfma_f32_16x16x16f16(vhi, pb[0][2 * nbp + 1], acc[0][db], 0, 0, 0);
        acc[1][db] = __builtin_amdgcn_mfma_f32_16x16x16f16(vhi, pb[1][2 * nbp + 1], acc[1][db], 0, 0, 0);
      }
    }
    __builtin_amdgcn_s_setprio(0);

    __syncthreads();
    if (more) {
      f16* lv = Vt + t * 8;
      *(f16x8*)(lv) = vv0;
      *(f16x8*)(lv + 2048) = vv1;
      *(f16x8*)(lv + 4096) = vv2;
      *(f16x8*)(lv + 6144) = vv3;
    }
    cur ^= 1;
  }

#pragma unroll
  for (int mi = 0; mi < 2; ++mi) {
    int qrow = q0 + w * 32 + mi * 16 + ln;
    if (g == 0) {
      pm[((size_t)s * 12 + h) * PMPITCH + qrow] = m_run[mi];
      pl[((size_t)s * 12 + h) * PMPITCH + qrow] = l_run[mi];
    }
#pragma unroll
    for (int db = 0; db < 8; ++db) {
      *(f32x4*)&Os[w][ln][4 * g] = acc[mi][db];
      asm volatile("s_waitcnt lgkmcnt(0)" ::: "memory");
#pragma unroll
      for (int r = 0; r < 4; ++r) {
        int q = q0 + w * 32 + mi * 16 + 4 * g + r;
        float val = Os[w][4 * g + r][ln];
        if (q < L_SEQ)
          pO[((size_t)s * L_SEQ + q) * DIMSZ + h * HDIM + db * 16 + ln] = val;
      }
      asm volatile("s_waitcnt lgkmcnt(0)" ::: "memory");
    }
  }
}

// ---- combine split-K partials -> aos fp16 blocked-swizzled (A of out-GEMM) ----
__global__ __launch_bounds__(256) void combine_k(
    const float* __restrict__ pO, const float* __restrict__ pm,
    const float* __restrict__ pl, f16* __restrict__ aos) {
  const int qt = blockIdx.x, h = blockIdx.y, t = threadIdx.x;
  const int row = t >> 1, d0 = (t & 1) * 64;
  const int q = min(qt * 128 + row, L_SEQ - 1);
  const float m0 = pm[(size_t)h * PMPITCH + q];
  const float m1 = pm[((size_t)12 + h) * PMPITCH + q];
  const float l0 = pl[(size_t)h * PMPITCH + q];
  const float l1 = pl[((size_t)12 + h) * PMPITCH + q];
  const float m = fmaxf(m0, m1);
  float w0 = exp2f(m0 - m), w1 = exp2f(m1 - m);
  const float rinv = 1.f / (w0 * l0 + w1 * l1);
  w0 *= rinv; w1 *= rinv;
  const float* o0 = &pO[(size_t)q * DIMSZ + h * HDIM + d0];
  const float* o1 = &pO[((size_t)L_SEQ + q) * DIMSZ + h * HDIM + d0];
  f16* outbase = aos + ((size_t)qt * 48 + h * 4) * 4096 + row * 32;
#pragma unroll
  for (int c8 = 0; c8 < 8; ++c8) {
    float a[8], bvals[8];
    *(float4*)&a[0] = *(const float4*)&o0[c8 * 8];
    *(float4*)&a[4] = *(const float4*)&o0[c8 * 8 + 4];
    *(float4*)&bvals[0] = *(const float4*)&o1[c8 * 8];
    *(float4*)&bvals[4] = *(const float4*)&o1[c8 * 8 + 4];
    f16x8 ov;
#pragma unroll
    for (int i = 0; i < 8; ++i) ov[i] = (f16)(w0 * a[i] + w1 * bvals[i]);
    int d = d0 + c8 * 8;
    int ktb = d >> 5;
    int s8 = (d & 31) >> 3;
    *(f16x8*)&outbase[(size_t)ktb * 4096 + ((s8 * 8) ^ ((row & 3) * 8))] = ov;
  }
}

extern "C" void kernel_launch(void* const* d_in, const int* in_sizes, int n_in,
                              void* d_out, int out_size, void* d_ws, size_t ws_size,
                              hipStream_t stream) {
  const float* x  = (const float*)d_in[0];
  const float* wq = (const float*)d_in[1];
  const float* bq = (const float*)d_in[2];
  const float* wk = (const float*)d_in[3];
  const float* bk = (const float*)d_in[4];
  const float* wv = (const float*)d_in[5];
  const float* bv = (const float*)d_in[6];
  const float* wo = (const float*)d_in[7];
  const float* bo = (const float*)d_in[8];
  const float* gq = (const float*)d_in[9];
  const float* gk = (const float*)d_in[10];
  const float* freqs = (const float*)d_in[11];
  float* out = (float*)d_out;
  float* ws = (float*)d_ws;

  // region A (2*LD f32): qh/kh/vh f16 (pre-attn), then pO (attn output partials)
  float* pO = ws;
  f16* qh = (f16*)ws;              // 3*LD f16 = 1.5*LD f32 < 2*LD ✓ (dead before pO written)
  f16* kh = qh + LDSZ;
  f16* vh = kh + LDSZ;
  // region B: aos + pm/pl
  f16* aos = (f16*)(ws + 2 * LDSZ);          // XSZ halves
  float* pm = (float*)(aos + XSZ);           // 113,664 f32
  float* pl = pm + 2 * 12 * PMPITCH;
  // region C: fp16 staging
  f16* xs  = (f16*)(pl + 2 * 12 * PMPITCH);  // XSZ -> later q16
  f16* k16 = xs + XSZ;
  f16* v16 = k16 + XSZ;
  f16* whi = v16 + XSZ;                      // 4*WSZ (wq,wk,wv,wo)
  f16* q16 = xs;                             // overlay after QKV GEMM reads xs
  f16* wo_hi = whi + 3 * (size_t)WSZ;

  dim3 blk(256);
  split_all<<<dim3(48, 85), blk, 0, stream>>>(x, wq, wk, wv, wo, xs, whi);
  gemm_f16_t<1><<<dim3(37, 36), blk, 0, stream>>>(xs, whi, bq, bk, bv, nullptr, qh, L_SEQ);
  norm_v<<<dim3(9360 + 888), blk, 0, stream>>>(qh, kh, gq, gk, freqs, q16, k16, vh, v16);
  attn_split<<<dim3(37 * 24), blk, 0, stream>>>(q16, k16, v16, pO, pm, pl);
  combine_k<<<dim3(37, 12), blk, 0, stream>>>(pO, pm, pl, aos);
  gemm_f16_t<0><<<dim3(37, 12), blk, 0, stream>>>(aos, wo_hi, bo, bo, bo, out, nullptr, L_SEQ);
}